// Round 6
// baseline (148.237 us; speedup 1.0000x reference)
//
#include <hip/hip_runtime.h>

#define BATCH 8192
#define INC   512
#define OUTC  512
#define NB    8
#define KDIM  (INC * NB)        // 4096
#define SPLITK 2
#define KH    (KDIM / SPLITK)   // 2048 k per block
#define IHALF (INC / SPLITK)    // 256 i per block
#define BM 128
#define BN 128
#define BK 64
#define NKT (KH / BK)           // 32
#define THREADS 256
#define ABUF (BM * BK)          // 8192 shorts = 16 KB
#define BBUF (BN * BK)

typedef __attribute__((ext_vector_type(8))) short bf16x8;
typedef __attribute__((ext_vector_type(4))) float f32x4;
typedef __attribute__((ext_vector_type(4))) int   i32x4;

// truncate-pack two fp32 into two bf16 (lo -> low 16 bits) in one v_perm_b32
static __device__ __forceinline__ unsigned int pk2(float lo, float hi) {
    return __builtin_amdgcn_perm(__builtin_bit_cast(unsigned int, hi),
                                 __builtin_bit_cast(unsigned int, lo),
                                 0x07060302u);
}

// ---- prepass: W fp32 -> bf16 (RNE) ----
__global__ __launch_bounds__(256)
void w_prepass(const float* __restrict__ W, unsigned short* __restrict__ Wb) {
    const int base = (blockIdx.x * 256 + threadIdx.x) * 8;
    const float4 a = *(const float4*)(W + base);
    const float4 b = *(const float4*)(W + base + 4);
    const float v[8] = {a.x, a.y, a.z, a.w, b.x, b.y, b.z, b.w};
    unsigned int r[8];
#pragma unroll
    for (int i = 0; i < 8; ++i) {
        unsigned int t = __builtin_bit_cast(unsigned int, v[i]);
        t += 0x7FFFu + ((t >> 16) & 1u);
        r[i] = t >> 16;
    }
    *(i32x4*)(Wb + base) = (i32x4){(int)(r[0] | (r[1] << 16)), (int)(r[2] | (r[3] << 16)),
                                   (int)(r[4] | (r[5] << 16)), (int)(r[6] | (r[7] << 16))};
}

// LDS layout for BOTH A and B (XOR-swizzled, verified r3):
//   element (row, kblk) at short offset row*64 + (kblk ^ (row&7))*8
template <bool DMA>
__global__ __launch_bounds__(THREADS, 2)
void fused_gemm(const float* __restrict__ X,    // (BATCH, INC)
                const void*  __restrict__ Wsrc, // bf16 ws or fp32 W
                const float* __restrict__ CEN,
                const float* __restrict__ SLP,
                float* __restrict__ Y)          // (BATCH, OUTC), pre-zeroed
{
    __shared__ short As[2][ABUF];   // 2 x 16 KB
    __shared__ short Bs[2][BBUF];   // 2 x 16 KB

    const int tid  = threadIdx.x;
    const int lane = tid & 63;
    const int wave = tid >> 6;      // 0..3
    const int wm   = wave & 1;      // 2 m-waves of 64 rows
    const int wn   = wave >> 1;     // 2 n-waves of 64 cols
    const int l15  = lane & 15;
    const int h    = lane >> 4;     // 0..3
    const int low3 = lane & 7;

    const int b0 = blockIdx.x * BM;
    const int j0 = blockIdx.y * BN;
    const int kz = blockIdx.z;

    // sigmoid: s_m(x) = 1/(1 + exp2(pc*x + q0) * R^m)
    const float L2E = 1.4426950408889634f;
    const float g2  = 2.0f * SLP[0] * L2E;
    const float pc  = -g2;
    const float q0  = g2 * CEN[0];
    const float R   = __builtin_amdgcn_exp2f(g2 * (CEN[1] - CEN[0]));

    // fragment read bases (per ks half); +mf*16*64 / +nf*16*64 in loop
    const short* const arp0 = &As[0][(wm * 64 + l15) * 64 + ((0 + h) ^ low3) * 8];
    const short* const arp1 = &As[0][(wm * 64 + l15) * 64 + ((4 + h) ^ low3) * 8];
    const short* const brp0 = &Bs[0][(wn * 64 + l15) * 64 + ((0 + h) ^ low3) * 8];
    const short* const brp1 = &Bs[0][(wn * 64 + l15) * 64 + ((4 + h) ^ low3) * 8];

    // B DMA global-side swizzle
    const int dma_r  = lane >> 3;
    const int dma_kb = (lane & 7) ^ dma_r;

    // A staging role: thread -> (row, 4 of the 8 kblks of the tile)
    const int srow = tid >> 1;              // 0..127
    const int sib  = (tid & 1) * 4;         // first kblk (= i-local index)
    const int sxor = srow & 7;
    const float* xrow = X + (size_t)(b0 + srow) * INC + kz * IHALF + sib;

    f32x4 acc[4][4];
#pragma unroll
    for (int i = 0; i < 4; ++i)
#pragma unroll
        for (int j = 0; j < 4; ++j)
            acc[i][j] = (f32x4){0.f, 0.f, 0.f, 0.f};

#define STAGE(kt, buf, xq)                                                     \
    {                                                                          \
        if constexpr (DMA) {                                                   \
            const unsigned short* Wb = (const unsigned short*)Wsrc;            \
            _Pragma("unroll")                                                  \
            for (int q = 0; q < 4; ++q) {                                      \
                const int cc = wave * 4 + q;   /* 1 KB chunk, wave-uniform */  \
                const unsigned short* gp = Wb                                  \
                    + (size_t)(j0 + cc * 8 + dma_r) * KDIM + kz * KH           \
                    + (kt) * BK + dma_kb * 8;                                  \
                __builtin_amdgcn_global_load_lds(                              \
                    (const __attribute__((address_space(1))) void*)gp,         \
                    (__attribute__((address_space(3))) void*)(&Bs[buf][cc * 512]), \
                    16, 0, 0);                                                 \
            }                                                                  \
        } else {                                                               \
            const float* Wf = (const float*)Wsrc;                              \
            const int row = tid >> 1;                                          \
            const int q4  = tid & 1;                                           \
            const float* wp = Wf + (size_t)(j0 + row) * KDIM + kz * KH         \
                            + (kt) * BK + q4 * 32;                             \
            _Pragma("unroll")                                                  \
            for (int p = 0; p < 4; ++p) {                                      \
                const int kb = q4 * 4 + p;                                     \
                const float4 c0 = ((const float4*)wp)[2 * p];                  \
                const float4 c1 = ((const float4*)wp)[2 * p + 1];              \
                *(i32x4*)(&Bs[buf][row * 64 + ((kb ^ (row & 7)) * 8)]) =       \
                    (i32x4){(int)pk2(c0.x, c0.y), (int)pk2(c0.z, c0.w),        \
                            (int)pk2(c1.x, c1.y), (int)pk2(c1.z, c1.w)};       \
            }                                                                  \
        }                                                                      \
        const float xe[4] = {(xq).x, (xq).y, (xq).z, (xq).w};                  \
        _Pragma("unroll")                                                      \
        for (int e = 0; e < 4; ++e) {                                          \
            float ev = __builtin_amdgcn_exp2f(fmaf(pc, xe[e], q0));            \
            float s[NB];                                                       \
            _Pragma("unroll")                                                  \
            for (int m = 0; m < NB; ++m) {                                     \
                s[m] = __builtin_amdgcn_rcpf(1.0f + ev);                       \
                ev *= R;                                                       \
            }                                                                  \
            *(i32x4*)(&As[buf][srow * 64 + (((sib + e) ^ sxor) * 8)]) =        \
                (i32x4){(int)pk2(s[0], s[1]), (int)pk2(s[2], s[3]),            \
                        (int)pk2(s[4], s[5]), (int)pk2(s[6], s[7])};           \
        }                                                                      \
    }

    // prologue: stage kt=0, prefetch x for kt=1
    float4 xc = *(const float4*)(xrow);
    STAGE(0, 0, xc);
    float4 xn = *(const float4*)(xrow + 8);

    for (int kt = 0; kt < NKT; ++kt) {
        const int cur = kt & 1;

        __syncthreads();   // buf[cur] ready (vmcnt/lgkm drained); prior reads of buf[1-cur] done

        if (kt + 1 < NKT) {
            STAGE(kt + 1, 1 - cur, xn);   // independent of this iter's MFMAs
            const int ktn = (kt + 2 < NKT) ? (kt + 2) : (NKT - 1);
            xn = *(const float4*)(xrow + ktn * 8);
        }

        // MFMA on buf[cur]
#pragma unroll
        for (int ks = 0; ks < 2; ++ks) {
            const short* ar = (ks ? arp1 : arp0) + cur * ABUF;
            const short* br = (ks ? brp1 : brp0) + cur * BBUF;
            bf16x8 af[4], bfr[4];
#pragma unroll
            for (int mf = 0; mf < 4; ++mf)
                af[mf] = *(const bf16x8*)(ar + mf * (16 * 64));
#pragma unroll
            for (int nf = 0; nf < 4; ++nf)
                bfr[nf] = *(const bf16x8*)(br + nf * (16 * 64));
#pragma unroll
            for (int mf = 0; mf < 4; ++mf)
#pragma unroll
                for (int nf = 0; nf < 4; ++nf)
                    acc[mf][nf] = __builtin_amdgcn_mfma_f32_16x16x32_bf16(
                        af[mf], bfr[nf], acc[mf][nf], 0, 0, 0);
        }
    }
#undef STAGE

    // epilogue: C/D layout col=lane&15, row=(lane>>4)*4+reg ; accumulate across kz
    const int rowb = b0 + wm * 64 + h * 4;
    const int colb = j0 + wn * 64 + l15;
#pragma unroll
    for (int mf = 0; mf < 4; ++mf)
#pragma unroll
        for (int nf = 0; nf < 4; ++nf)
#pragma unroll
            for (int r = 0; r < 4; ++r)
                atomicAdd(&Y[(size_t)(rowb + mf * 16 + r) * OUTC + (colb + nf * 16)],
                          acc[mf][nf][r]);
}

extern "C" void kernel_launch(void* const* d_in, const int* in_sizes, int n_in,
                              void* d_out, int out_size, void* d_ws, size_t ws_size,
                              hipStream_t stream) {
    const float* X   = (const float*)d_in[0];
    const float* W   = (const float*)d_in[1];
    const float* CEN = (const float*)d_in[2];
    const float* SLP = (const float*)d_in[3];
    float* Y = (float*)d_out;

    hipMemsetAsync(d_out, 0, (size_t)out_size * sizeof(float), stream);

    static_assert(BATCH % BM == 0 && OUTC % BN == 0 && KH % BK == 0, "tiling");
    dim3 grid(BATCH / BM, OUTC / BN, SPLITK);   // 64 x 4 x 2 = 512 blocks

    const size_t WB_BYTES = (size_t)OUTC * KDIM * sizeof(unsigned short); // 4 MB
    if (ws_size >= WB_BYTES) {
        unsigned short* Wb = (unsigned short*)d_ws;
        w_prepass<<<dim3((OUTC * KDIM) / (8 * 256)), dim3(256), 0, stream>>>(W, Wb);
        fused_gemm<true><<<grid, dim3(THREADS), 0, stream>>>(X, Wb, CEN, SLP, Y);
    } else {
        fused_gemm<false><<<grid, dim3(THREADS), 0, stream>>>(X, (const void*)W,
                                                              CEN, SLP, Y);
    }
}